// Round 3
// baseline (360.427 us; speedup 1.0000x reference)
//
#include <hip/hip_runtime.h>
#include <math.h>

#define B_   64
#define T_   1024
#define AD   128
#define RD   1024
#define ED   512
#define NF   32
#define KS   31
#define PADW 15

#define SA   72   // As/Bs LDS row stride (shorts)
#define SL   40   // loc LDS row stride (shorts)

typedef short bf16x8 __attribute__((ext_vector_type(8)));
typedef float f32x4  __attribute__((ext_vector_type(4)));

__device__ __forceinline__ short f2bf(float x) {
  union { float f; unsigned u; } v; v.f = x;
  unsigned r = (v.u + 0x7FFFu + ((v.u >> 16) & 1u)) >> 16;  // RNE
  return (short)r;
}

__device__ __forceinline__ float tanh_fast(float x) {
  float t = __expf(2.0f * x);
  return (t - 1.0f) * __builtin_amdgcn_rcpf(t + 1.0f);
}

// ---------------------------------------------------------------------------
// PREP (merged): blocks [0,68) bf16-convert Wk/Wlp; [68,580) location conv;
// [580,644) q_proj.
__global__ __launch_bounds__(256) void prep_kernel(
    const float* __restrict__ Wk, const float* __restrict__ Wlp,
    const float* __restrict__ awc, const float* __restrict__ Wc,
    const float* __restrict__ query, const float* __restrict__ Wq,
    short* __restrict__ Wk16, short* __restrict__ Wlp16,
    short* __restrict__ loc_g, float* __restrict__ qp) {
  __shared__ float sh_awc[128 + KS - 1];
  __shared__ float sh_wc[NF * KS];
  __shared__ float sh_q[RD];
  __shared__ float sh_red[AD];
  const int blk = blockIdx.x, tid = threadIdx.x;

  if (blk < 68) {
    // ---- weight bf16 conversion: 16384 float4 (Wk) + 1024 float4 (Wlp)
    int p = blk * 256 + tid;
    const float* src; short* dst; int off;
    if (p < 16384) { src = Wk; dst = Wk16; off = p; }
    else           { src = Wlp; dst = Wlp16; off = p - 16384; }
    float4 v = *(const float4*)&src[off * 4];
    short4 h = { f2bf(v.x), f2bf(v.y), f2bf(v.z), f2bf(v.w) };
    *(short4*)&dst[off * 4] = h;
  } else if (blk < 580) {
    // ---- location conv -> loc_g[(b*T+t)*NF + f] (bf16)
    int cb = blk - 68;
    int b = cb >> 3, t0 = (cb & 7) * 128;
    for (int i = tid; i < NF * KS; i += 256) sh_wc[i] = Wc[i];
    if (tid < 128 + KS - 1) {
      int gt = t0 - PADW + tid;
      sh_awc[tid] = (gt >= 0 && gt < T_) ? awc[b * T_ + gt] : 0.0f;
    }
    __syncthreads();
    const int t = tid & 127, fh = (tid >> 7) * 16;
    for (int fq = 0; fq < 4; ++fq) {
      float s0 = 0.f, s1 = 0.f, s2 = 0.f, s3 = 0.f;
      const float* w0 = &sh_wc[(fh + fq * 4 + 0) * KS];
      const float* w1 = &sh_wc[(fh + fq * 4 + 1) * KS];
      const float* w2 = &sh_wc[(fh + fq * 4 + 2) * KS];
      const float* w3 = &sh_wc[(fh + fq * 4 + 3) * KS];
#pragma unroll
      for (int k = 0; k < KS; ++k) {
        float aw = sh_awc[t + k];
        s0 += w0[k] * aw; s1 += w1[k] * aw; s2 += w2[k] * aw; s3 += w3[k] * aw;
      }
      short4 h = { f2bf(s0), f2bf(s1), f2bf(s2), f2bf(s3) };
      *(short4*)&loc_g[((size_t)(b * T_ + t0 + t)) * NF + fh + fq * 4] = h;
    }
  } else {
    // ---- q_proj[b][a] = dot(query[b], Wq[a]); 2-way k-split
    int b = blk - 580;
    *(float4*)&sh_q[tid * 4] = *(const float4*)&query[b * RD + tid * 4];
    __syncthreads();
    const int a = tid & 127, kh = tid >> 7;
    const float* wr = &Wq[(size_t)a * RD + kh * 512];
    const float* qr = &sh_q[kh * 512];
    float acc = 0.f;
    for (int e = 0; e < 512; e += 4) {
      float4 w = *(const float4*)&wr[e];
      acc += w.x * qr[e] + w.y * qr[e + 1] + w.z * qr[e + 2] + w.w * qr[e + 3];
    }
    if (kh == 1) sh_red[a] = acc;
    __syncthreads();
    if (kh == 0) qp[b * AD + a] = acc + sh_red[a];
  }
}

// ---------------------------------------------------------------------------
// SCORES: 64t x 128a tile per block, grid(16,64). 4 waves, each 64x32.
// Register-prefetch of next K-chunk overlaps MFMA. K = 512 (keys) + 32 (loc).
__global__ __launch_bounds__(256) void scores_kernel(
    const float* __restrict__ keys, const short* __restrict__ Wk16,
    const short* __restrict__ Wlp16, const short* __restrict__ loc_g,
    const float* __restrict__ qp, const float* __restrict__ Wa,
    float* __restrict__ scores) {
  __shared__ alignas(16) short As[64 * SA];
  __shared__ alignas(16) short Bs[128 * SA];
  __shared__ alignas(16) short Ls[64 * SL];
  __shared__ float qp_s[AD], wa_s[AD];
  __shared__ float sc_s[64 * 4];

  const int tid = threadIdx.x;
  const int b = blockIdx.y, t0 = blockIdx.x * 64;
  const int lane = tid & 63, wave = tid >> 6;
  const int m16 = lane & 15, s4 = lane >> 4;

  if (tid < AD) { qp_s[tid] = qp[b * AD + tid]; wa_s[tid] = Wa[tid]; }
  {  // stage loc tile: 64 rows x 32 bf16 = 256 int4 slots
    int r = tid >> 2, c = tid & 3;
    *(int4*)&Ls[r * SL + c * 8] =
        *(const int4*)&loc_g[((size_t)(b * T_ + t0 + r)) * NF + c * 8];
  }

  f32x4 acc[4][2];
#pragma unroll
  for (int mt = 0; mt < 4; ++mt)
#pragma unroll
    for (int nt = 0; nt < 2; ++nt) acc[mt][nt] = (f32x4){0.f, 0.f, 0.f, 0.f};

  const float* kb = keys + ((size_t)(b * T_ + t0)) * ED;
  float4 pa[4]; int4 pb[4]; int4 pw[2];

  // initial prefetch: chunk 0
#pragma unroll
  for (int i = 0; i < 4; ++i) {
    int p = i * 256 + tid;
    pa[i] = *(const float4*)&kb[(size_t)(p >> 4) * ED + (p & 15) * 4];
  }
#pragma unroll
  for (int i = 0; i < 4; ++i) {
    int p = i * 256 + tid;
    pb[i] = *(const int4*)&Wk16[(size_t)(p >> 3) * ED + (p & 7) * 8];
  }

  for (int kc = 0; kc < 8; ++kc) {
    __syncthreads();  // previous MFMA reads done
#pragma unroll
    for (int i = 0; i < 4; ++i) {
      int p = i * 256 + tid, r = p >> 4, e4 = p & 15;
      short4 h = { f2bf(pa[i].x), f2bf(pa[i].y), f2bf(pa[i].z), f2bf(pa[i].w) };
      *(short4*)&As[r * SA + e4 * 4] = h;
    }
#pragma unroll
    for (int i = 0; i < 4; ++i) {
      int p = i * 256 + tid, r = p >> 3, c8 = p & 7;
      *(int4*)&Bs[r * SA + c8 * 8] = pb[i];
    }
    __syncthreads();
    // issue next-chunk loads; results not needed until after next barrier
    if (kc < 7) {
      int ko = (kc + 1) * 64;
#pragma unroll
      for (int i = 0; i < 4; ++i) {
        int p = i * 256 + tid;
        pa[i] = *(const float4*)&kb[(size_t)(p >> 4) * ED + ko + (p & 15) * 4];
      }
#pragma unroll
      for (int i = 0; i < 4; ++i) {
        int p = i * 256 + tid;
        pb[i] = *(const int4*)&Wk16[(size_t)(p >> 3) * ED + ko + (p & 7) * 8];
      }
    } else {
#pragma unroll
      for (int i = 0; i < 2; ++i) {
        int p = i * 256 + tid;
        pw[i] = *(const int4*)&Wlp16[(p >> 2) * NF + (p & 3) * 8];
      }
    }
#pragma unroll
    for (int kk = 0; kk < 64; kk += 32) {
      const int ko = kk + s4 * 8;
      bf16x8 af[4], bfr[2];
#pragma unroll
      for (int mt = 0; mt < 4; ++mt)
        af[mt] = *(const bf16x8*)&As[(mt * 16 + m16) * SA + ko];
#pragma unroll
      for (int nt = 0; nt < 2; ++nt)
        bfr[nt] = *(const bf16x8*)&Bs[(wave * 32 + nt * 16 + m16) * SA + ko];
#pragma unroll
      for (int mt = 0; mt < 4; ++mt)
#pragma unroll
        for (int nt = 0; nt < 2; ++nt)
          acc[mt][nt] = __builtin_amdgcn_mfma_f32_16x16x32_bf16(
              af[mt], bfr[nt], acc[mt][nt], 0, 0, 0);
    }
  }

  // loc chunk (K=32): A = Ls, B = Wlp16 (staged from pw)
  __syncthreads();
#pragma unroll
  for (int i = 0; i < 2; ++i) {
    int p = i * 256 + tid;
    *(int4*)&Bs[(p >> 2) * SA + (p & 3) * 8] = pw[i];
  }
  __syncthreads();
  {
    const int ko = s4 * 8;
    bf16x8 af[4], bfr[2];
#pragma unroll
    for (int mt = 0; mt < 4; ++mt)
      af[mt] = *(const bf16x8*)&Ls[(mt * 16 + m16) * SL + ko];
#pragma unroll
    for (int nt = 0; nt < 2; ++nt)
      bfr[nt] = *(const bf16x8*)&Bs[(wave * 32 + nt * 16 + m16) * SA + ko];
#pragma unroll
    for (int mt = 0; mt < 4; ++mt)
#pragma unroll
      for (int nt = 0; nt < 2; ++nt)
        acc[mt][nt] = __builtin_amdgcn_mfma_f32_16x16x32_bf16(
            af[mt], bfr[nt], acc[mt][nt], 0, 0, 0);
  }

  // epilogue: +qp, tanh, Wa-dot, reduce over a (16 lanes + 2 nt + 4 waves)
  float qv[2], wv[2];
#pragma unroll
  for (int nt = 0; nt < 2; ++nt) {
    int a = wave * 32 + nt * 16 + m16;
    qv[nt] = qp_s[a]; wv[nt] = wa_s[a];
  }
#pragma unroll
  for (int mt = 0; mt < 4; ++mt) {
#pragma unroll
    for (int r = 0; r < 4; ++r) {
      float p = wv[0] * tanh_fast(acc[mt][0][r] + qv[0]) +
                wv[1] * tanh_fast(acc[mt][1][r] + qv[1]);
      p += __shfl_xor(p, 1); p += __shfl_xor(p, 2);
      p += __shfl_xor(p, 4); p += __shfl_xor(p, 8);
      if (m16 == 0) sc_s[(mt * 16 + s4 * 4 + r) * 4 + wave] = p;
    }
  }
  __syncthreads();
  if (tid < 64) {
    float4 v = *(const float4*)&sc_s[tid * 4];
    scores[(size_t)b * T_ + t0 + tid] = v.x + v.y + v.z + v.w;
  }
}

// ---------------------------------------------------------------------------
__global__ __launch_bounds__(256) void softmax_kernel(
    const float* __restrict__ scores, const unsigned char* __restrict__ mask,
    float* __restrict__ attn) {
  const int b = blockIdx.x, tid = threadIdx.x;
  __shared__ float redm[4], reds[4];

  float4 s4 = *(const float4*)&scores[b * T_ + tid * 4];
  uchar4 m4 = *(const uchar4*)&mask[b * T_ + tid * 4];
  if (m4.x) s4.x = -INFINITY;
  if (m4.y) s4.y = -INFINITY;
  if (m4.z) s4.z = -INFINITY;
  if (m4.w) s4.w = -INFINITY;

  float mx = fmaxf(fmaxf(s4.x, s4.y), fmaxf(s4.z, s4.w));
#pragma unroll
  for (int off = 32; off >= 1; off >>= 1) mx = fmaxf(mx, __shfl_xor(mx, off, 64));
  if ((tid & 63) == 0) redm[tid >> 6] = mx;
  __syncthreads();
  mx = fmaxf(fmaxf(redm[0], redm[1]), fmaxf(redm[2], redm[3]));

  float e0 = expf(s4.x - mx), e1 = expf(s4.y - mx);
  float e2 = expf(s4.z - mx), e3 = expf(s4.w - mx);
  float sum = e0 + e1 + e2 + e3;
#pragma unroll
  for (int off = 32; off >= 1; off >>= 1) sum += __shfl_xor(sum, off, 64);
  if ((tid & 63) == 0) reds[tid >> 6] = sum;
  __syncthreads();
  sum = reds[0] + reds[1] + reds[2] + reds[3];

  float inv = 1.0f / sum;
  float4 o4 = { e0 * inv, e1 * inv, e2 * inv, e3 * inv };
  *(float4*)&attn[b * T_ + tid * 4] = o4;
}

// ---------------------------------------------------------------------------
// WVSUM: wvp[b][p][e] partials over 32-row groups; grid(16,64), 64 rows/block.
__global__ __launch_bounds__(256) void wvsum_kernel(
    const float* __restrict__ values, const float* __restrict__ attn,
    float* __restrict__ wvp) {
  const int tc = blockIdx.x, b = blockIdx.y, tid = threadIdx.x;
  __shared__ float at_s[64];
  if (tid < 64) at_s[tid] = attn[b * T_ + tc * 64 + tid];
  __syncthreads();
  const int e4 = tid & 127, th = tid >> 7;
  const float* vb =
      values + ((size_t)(b * T_ + tc * 64 + th * 32)) * ED + e4 * 4;
  float4 acc = {0.f, 0.f, 0.f, 0.f};
#pragma unroll 8
  for (int t = 0; t < 32; ++t) {
    float a = at_s[th * 32 + t];
    float4 v = *(const float4*)&vb[(size_t)t * ED];
    acc.x = fmaf(a, v.x, acc.x); acc.y = fmaf(a, v.y, acc.y);
    acc.z = fmaf(a, v.z, acc.z); acc.w = fmaf(a, v.w, acc.w);
  }
  *(float4*)&wvp[((size_t)(b * 32 + tc * 2 + th)) * ED + e4 * 4] = acc;
}

// ---------------------------------------------------------------------------
// CONTEXT: ctx[b][f] = sum_e Wv[f][e] * (sum_p wvp[b][p][e]); grid(4,64).
__global__ __launch_bounds__(256) void context_kernel(
    const float* __restrict__ wvp, const float* __restrict__ Wv,
    float* __restrict__ ctx) {
  const int fq = blockIdx.x, b = blockIdx.y, tid = threadIdx.x;
  __shared__ float wv_s[ED];
  __shared__ float red[128];
  for (int e = tid; e < ED; e += 256) {
    float s = 0.f;
    const float* base = &wvp[(size_t)b * 32 * ED + e];
#pragma unroll
    for (int p = 0; p < 32; ++p) s += base[p * ED];
    wv_s[e] = s;
  }
  __syncthreads();
  const int fl = tid & 127, eh = tid >> 7;
  const int f = fq * 128 + fl;
  const float* wr = &Wv[(size_t)f * ED + eh * 256];
  const float* qr = &wv_s[eh * 256];
  float acc = 0.f;
  for (int e = 0; e < 256; e += 4) {
    float4 w = *(const float4*)&wr[e];
    acc += w.x * qr[e] + w.y * qr[e + 1] + w.z * qr[e + 2] + w.w * qr[e + 3];
  }
  if (eh == 1) red[fl] = acc;
  __syncthreads();
  if (eh == 0) ctx[b * ED + f] = acc + red[fl];
}

// ---------------------------------------------------------------------------
extern "C" void kernel_launch(void* const* d_in, const int* in_sizes, int n_in,
                              void* d_out, int out_size, void* d_ws, size_t ws_size,
                              hipStream_t stream) {
  const float* query = (const float*)d_in[0];
  const float* keys  = (const float*)d_in[1];
  const float* values= (const float*)d_in[2];
  const float* awc   = (const float*)d_in[3];
  const unsigned char* mask = (const unsigned char*)d_in[4];
  const float* Wc    = (const float*)d_in[5];
  const float* Wlp   = (const float*)d_in[6];
  const float* Wq    = (const float*)d_in[7];
  const float* Wk    = (const float*)d_in[8];
  const float* Wv    = (const float*)d_in[9];
  const float* Wa    = (const float*)d_in[10];

  float* ctx  = (float*)d_out;              // (64,512)
  float* attn = (float*)d_out + B_ * ED;    // (64,1024)

  float* ws = (float*)d_ws;
  float* qp      = ws;                                     // 8192 f
  float* scoresB = qp + B_ * AD;                           // 65536 f
  float* wvp     = scoresB + B_ * T_;                      // 64*32*512 f
  short* Wk16    = (short*)(wvp + (size_t)B_ * 32 * ED);   // 65536 sh
  short* Wlp16   = Wk16 + AD * ED;                         // 4096 sh
  short* loc_g   = Wlp16 + AD * NF;                        // 64*1024*32 sh

  prep_kernel<<<644, 256, 0, stream>>>(Wk, Wlp, awc, Wc, query, Wq,
                                       Wk16, Wlp16, loc_g, qp);
  scores_kernel<<<dim3(16, B_), 256, 0, stream>>>(keys, Wk16, Wlp16, loc_g,
                                                  qp, Wa, scoresB);
  softmax_kernel<<<B_, 256, 0, stream>>>(scoresB, mask, attn);
  wvsum_kernel<<<dim3(16, B_), 256, 0, stream>>>(values, attn, wvp);
  context_kernel<<<dim3(4, B_), 256, 0, stream>>>(wvp, Wv, ctx);
}

// Round 4
// 347.877 us; speedup vs baseline: 1.0361x; 1.0361x over previous
//
#include <hip/hip_runtime.h>
#include <math.h>

#define B_   64
#define T_   1024
#define AD   128
#define RD   1024
#define ED   512
#define NF   32
#define KS   31
#define PADW 15

typedef short bf16x8 __attribute__((ext_vector_type(8)));
typedef float f32x4  __attribute__((ext_vector_type(4)));

typedef __attribute__((address_space(1))) unsigned gu32;
typedef __attribute__((address_space(3))) unsigned lu32;

// async global->LDS, 16B per lane. LDS dest = wave-uniform base + lane*16.
__device__ __forceinline__ void gll16(const void* g, void* l) {
  __builtin_amdgcn_global_load_lds(
      (gu32*)(unsigned long long)g,
      (lu32*)(unsigned)(unsigned long long)l, 16, 0, 0);
}

__device__ __forceinline__ short f2bf(float x) {
  union { float f; unsigned u; } v; v.f = x;
  unsigned r = (v.u + 0x7FFFu + ((v.u >> 16) & 1u)) >> 16;  // RNE
  return (short)r;
}

__device__ __forceinline__ float tanh_fast(float x) {
  float t = __expf(2.0f * x);
  return (t - 1.0f) * __builtin_amdgcn_rcpf(t + 1.0f);
}

// ---------------------------------------------------------------------------
// PREP: [0,2048) keys fp32->bf16; [2048,2116) Wk/Wlp bf16; [2116,2628) conv;
// [2628,2692) q_proj.
#define KB_  2048
__global__ __launch_bounds__(256) void prep_kernel(
    const float* __restrict__ keys, const float* __restrict__ Wk,
    const float* __restrict__ Wlp, const float* __restrict__ awc,
    const float* __restrict__ Wc, const float* __restrict__ query,
    const float* __restrict__ Wq, short* __restrict__ keys16,
    short* __restrict__ Wk16, short* __restrict__ Wlp16,
    short* __restrict__ loc_g, float* __restrict__ qp) {
  __shared__ float sh_awc[128 + KS - 1];
  __shared__ float sh_wc[NF * KS];
  __shared__ float sh_q[RD];
  __shared__ float sh_red[AD];
  const int blk = blockIdx.x, tid = threadIdx.x;

  if (blk < KB_) {
    // keys -> bf16: 8388608 float4 total, 4096 per block, 16 per thread
    size_t base = (size_t)blk * 4096 + tid;
#pragma unroll
    for (int i = 0; i < 16; ++i) {
      size_t p = base + (size_t)i * 256;
      float4 v = *(const float4*)&keys[p * 4];
      short4 h = { f2bf(v.x), f2bf(v.y), f2bf(v.z), f2bf(v.w) };
      *(short4*)&keys16[p * 4] = h;
    }
  } else if (blk < KB_ + 68) {
    int p = (blk - KB_) * 256 + tid;
    const float* src; short* dst; int off;
    if (p < 16384) { src = Wk; dst = Wk16; off = p; }
    else           { src = Wlp; dst = Wlp16; off = p - 16384; }
    float4 v = *(const float4*)&src[off * 4];
    short4 h = { f2bf(v.x), f2bf(v.y), f2bf(v.z), f2bf(v.w) };
    *(short4*)&dst[off * 4] = h;
  } else if (blk < KB_ + 68 + 512) {
    // location conv -> loc_g[(b*T+t)*NF + f] (bf16)
    int cb = blk - (KB_ + 68);
    int b = cb >> 3, t0 = (cb & 7) * 128;
    for (int i = tid; i < NF * KS; i += 256) sh_wc[i] = Wc[i];
    if (tid < 128 + KS - 1) {
      int gt = t0 - PADW + tid;
      sh_awc[tid] = (gt >= 0 && gt < T_) ? awc[b * T_ + gt] : 0.0f;
    }
    __syncthreads();
    const int t = tid & 127, fh = (tid >> 7) * 16;
    for (int fq = 0; fq < 4; ++fq) {
      float s0 = 0.f, s1 = 0.f, s2 = 0.f, s3 = 0.f;
      const float* w0 = &sh_wc[(fh + fq * 4 + 0) * KS];
      const float* w1 = &sh_wc[(fh + fq * 4 + 1) * KS];
      const float* w2 = &sh_wc[(fh + fq * 4 + 2) * KS];
      const float* w3 = &sh_wc[(fh + fq * 4 + 3) * KS];
#pragma unroll
      for (int k = 0; k < KS; ++k) {
        float aw = sh_awc[t + k];
        s0 += w0[k] * aw; s1 += w1[k] * aw; s2 += w2[k] * aw; s3 += w3[k] * aw;
      }
      short4 h = { f2bf(s0), f2bf(s1), f2bf(s2), f2bf(s3) };
      *(short4*)&loc_g[((size_t)(b * T_ + t0 + t)) * NF + fh + fq * 4] = h;
    }
  } else {
    // q_proj[b][a] = dot(query[b], Wq[a]); 2-way k-split
    int b = blk - (KB_ + 68 + 512);
    *(float4*)&sh_q[tid * 4] = *(const float4*)&query[b * RD + tid * 4];
    __syncthreads();
    const int a = tid & 127, kh = tid >> 7;
    const float* wr = &Wq[(size_t)a * RD + kh * 512];
    const float* qr = &sh_q[kh * 512];
    float acc = 0.f;
    for (int e = 0; e < 512; e += 4) {
      float4 w = *(const float4*)&wr[e];
      acc += w.x * qr[e] + w.y * qr[e + 1] + w.z * qr[e + 2] + w.w * qr[e + 3];
    }
    if (kh == 1) sh_red[a] = acc;
    __syncthreads();
    if (kh == 0) qp[b * AD + a] = acc + sh_red[a];
  }
}

// ---------------------------------------------------------------------------
// SCORES: 128t x 128a tile, grid(8,64). 4 waves 2x2 of 64x64. All staging via
// global_load_lds (16B), XOR-swizzled unpadded LDS (stride 64 shorts = 128B).
// loc chunk (K=32) computed FIRST reusing As/Bs at stride 32.
__global__ __launch_bounds__(256, 2) void scores_kernel(
    const short* __restrict__ keys16, const short* __restrict__ Wk16,
    const short* __restrict__ Wlp16, const short* __restrict__ loc_g,
    const float* __restrict__ qp, const float* __restrict__ Wa,
    float* __restrict__ scores) {
  __shared__ alignas(16) short As[128 * 64];
  __shared__ alignas(16) short Bs[128 * 64];
  __shared__ float qp_s[AD], wa_s[AD];
  __shared__ float sc_s[128 * 2];

  const int tid = threadIdx.x;
  const int b = blockIdx.y, t0 = blockIdx.x * 128;
  const int lane = tid & 63, wave = tid >> 6;
  const int wm = wave >> 1, wn = wave & 1;
  const int m16 = lane & 15, s4 = lane >> 4;

  if (tid < AD) { qp_s[tid] = qp[b * AD + tid]; wa_s[tid] = Wa[tid]; }

  // ---- stage loc (A) / Wlp (B): rows of 32 shorts = 4 x 16B blocks ----
  {
    const int r = lane >> 2, cb = lane & 3;  // 16 rows per instr
#pragma unroll
    for (int i = 0; i < 2; ++i) {
      int row = wave * 32 + i * 16;
      gll16(&loc_g[((size_t)(b * T_ + t0 + row + r)) * NF + cb * 8],
            &As[row * 32]);
      gll16(&Wlp16[(row + r) * NF + cb * 8], &Bs[row * 32]);
    }
  }
  __syncthreads();

  f32x4 acc[4][4];
  {  // loc MFMA chunk (K=32), stride-32 plain layout
    bf16x8 af[4], bfr[4];
#pragma unroll
    for (int mt = 0; mt < 4; ++mt)
      af[mt] = *(const bf16x8*)&As[(wm * 64 + mt * 16 + m16) * 32 + s4 * 8];
#pragma unroll
    for (int nt = 0; nt < 4; ++nt)
      bfr[nt] = *(const bf16x8*)&Bs[(wn * 64 + nt * 16 + m16) * 32 + s4 * 8];
#pragma unroll
    for (int mt = 0; mt < 4; ++mt)
#pragma unroll
      for (int nt = 0; nt < 4; ++nt)
        acc[mt][nt] = __builtin_amdgcn_mfma_f32_16x16x32_bf16(
            af[mt], bfr[nt], (f32x4){0.f, 0.f, 0.f, 0.f}, 0, 0, 0);
  }

  // ---- main loop: 8 chunks of BK=64 over keys16/Wk16 ----
  const int r8 = lane >> 3, cb8 = lane & 7;
  const int cbg = cb8 ^ r8;  // XOR swizzle: LDS slot cb8 holds global block cbg
  const size_t kb = ((size_t)(b * T_ + t0)) * ED;

  for (int kc = 0; kc < 8; ++kc) {
    __syncthreads();  // all waves done reading previous tile
#pragma unroll
    for (int i = 0; i < 4; ++i) {
      int row = wave * 32 + i * 8;
      gll16(&keys16[kb + (size_t)(row + r8) * ED + kc * 64 + cbg * 8],
            &As[row * 64]);
      gll16(&Wk16[(size_t)(row + r8) * ED + kc * 64 + cbg * 8],
            &Bs[row * 64]);
    }
    __syncthreads();  // drains vmcnt: LDS tile complete
#pragma unroll
    for (int kk2 = 0; kk2 < 2; ++kk2) {
      const int j = kk2 * 4 + s4;
      const int ca = (j ^ (m16 & 7)) * 8;
      bf16x8 af[4], bfr[4];
#pragma unroll
      for (int mt = 0; mt < 4; ++mt)
        af[mt] = *(const bf16x8*)&As[(wm * 64 + mt * 16 + m16) * 64 + ca];
#pragma unroll
      for (int nt = 0; nt < 4; ++nt)
        bfr[nt] = *(const bf16x8*)&Bs[(wn * 64 + nt * 16 + m16) * 64 + ca];
#pragma unroll
      for (int mt = 0; mt < 4; ++mt)
#pragma unroll
        for (int nt = 0; nt < 4; ++nt)
          acc[mt][nt] = __builtin_amdgcn_mfma_f32_16x16x32_bf16(
              af[mt], bfr[nt], acc[mt][nt], 0, 0, 0);
    }
  }

  // ---- epilogue: +qp, tanh, Wa-dot, reduce over a ----
  float qv[4], wv[4];
#pragma unroll
  for (int nt = 0; nt < 4; ++nt) {
    int a = wn * 64 + nt * 16 + m16;
    qv[nt] = qp_s[a]; wv[nt] = wa_s[a];
  }
#pragma unroll
  for (int mt = 0; mt < 4; ++mt) {
#pragma unroll
    for (int r = 0; r < 4; ++r) {
      float p = 0.f;
#pragma unroll
      for (int nt = 0; nt < 4; ++nt)
        p += wv[nt] * tanh_fast(acc[mt][nt][r] + qv[nt]);
      p += __shfl_xor(p, 1); p += __shfl_xor(p, 2);
      p += __shfl_xor(p, 4); p += __shfl_xor(p, 8);
      if (m16 == 0) sc_s[(wm * 64 + mt * 16 + s4 * 4 + r) * 2 + wn] = p;
    }
  }
  __syncthreads();
  if (tid < 128)
    scores[(size_t)b * T_ + t0 + tid] = sc_s[tid * 2] + sc_s[tid * 2 + 1];
}

// ---------------------------------------------------------------------------
__global__ __launch_bounds__(256) void softmax_kernel(
    const float* __restrict__ scores, const unsigned char* __restrict__ mask,
    float* __restrict__ attn) {
  const int b = blockIdx.x, tid = threadIdx.x;
  __shared__ float redm[4], reds[4];

  float4 s4 = *(const float4*)&scores[b * T_ + tid * 4];
  uchar4 m4 = *(const uchar4*)&mask[b * T_ + tid * 4];
  if (m4.x) s4.x = -INFINITY;
  if (m4.y) s4.y = -INFINITY;
  if (m4.z) s4.z = -INFINITY;
  if (m4.w) s4.w = -INFINITY;

  float mx = fmaxf(fmaxf(s4.x, s4.y), fmaxf(s4.z, s4.w));
#pragma unroll
  for (int off = 32; off >= 1; off >>= 1) mx = fmaxf(mx, __shfl_xor(mx, off, 64));
  if ((tid & 63) == 0) redm[tid >> 6] = mx;
  __syncthreads();
  mx = fmaxf(fmaxf(redm[0], redm[1]), fmaxf(redm[2], redm[3]));

  float e0 = expf(s4.x - mx), e1 = expf(s4.y - mx);
  float e2 = expf(s4.z - mx), e3 = expf(s4.w - mx);
  float sum = e0 + e1 + e2 + e3;
#pragma unroll
  for (int off = 32; off >= 1; off >>= 1) sum += __shfl_xor(sum, off, 64);
  if ((tid & 63) == 0) reds[tid >> 6] = sum;
  __syncthreads();
  sum = reds[0] + reds[1] + reds[2] + reds[3];

  float inv = 1.0f / sum;
  float4 o4 = { e0 * inv, e1 * inv, e2 * inv, e3 * inv };
  *(float4*)&attn[b * T_ + tid * 4] = o4;
}

// ---------------------------------------------------------------------------
__global__ __launch_bounds__(256) void wvsum_kernel(
    const float* __restrict__ values, const float* __restrict__ attn,
    float* __restrict__ wvp) {
  const int tc = blockIdx.x, b = blockIdx.y, tid = threadIdx.x;
  __shared__ float at_s[64];
  if (tid < 64) at_s[tid] = attn[b * T_ + tc * 64 + tid];
  __syncthreads();
  const int e4 = tid & 127, th = tid >> 7;
  const float* vb =
      values + ((size_t)(b * T_ + tc * 64 + th * 32)) * ED + e4 * 4;
  float4 acc = {0.f, 0.f, 0.f, 0.f};
#pragma unroll 8
  for (int t = 0; t < 32; ++t) {
    float a = at_s[th * 32 + t];
    float4 v = *(const float4*)&vb[(size_t)t * ED];
    acc.x = fmaf(a, v.x, acc.x); acc.y = fmaf(a, v.y, acc.y);
    acc.z = fmaf(a, v.z, acc.z); acc.w = fmaf(a, v.w, acc.w);
  }
  *(float4*)&wvp[((size_t)(b * 32 + tc * 2 + th)) * ED + e4 * 4] = acc;
}

// ---------------------------------------------------------------------------
__global__ __launch_bounds__(256) void context_kernel(
    const float* __restrict__ wvp, const float* __restrict__ Wv,
    float* __restrict__ ctx) {
  const int fq = blockIdx.x, b = blockIdx.y, tid = threadIdx.x;
  __shared__ float wv_s[ED];
  __shared__ float red[128];
  for (int e = tid; e < ED; e += 256) {
    float s = 0.f;
    const float* base = &wvp[(size_t)b * 32 * ED + e];
#pragma unroll
    for (int p = 0; p < 32; ++p) s += base[p * ED];
    wv_s[e] = s;
  }
  __syncthreads();
  const int fl = tid & 127, eh = tid >> 7;
  const int f = fq * 128 + fl;
  const float* wr = &Wv[(size_t)f * ED + eh * 256];
  const float* qr = &wv_s[eh * 256];
  float acc = 0.f;
  for (int e = 0; e < 256; e += 4) {
    float4 w = *(const float4*)&wr[e];
    acc += w.x * qr[e] + w.y * qr[e + 1] + w.z * qr[e + 2] + w.w * qr[e + 3];
  }
  if (eh == 1) red[fl] = acc;
  __syncthreads();
  if (eh == 0) ctx[b * ED + f] = acc + red[fl];
}

// ---------------------------------------------------------------------------
extern "C" void kernel_launch(void* const* d_in, const int* in_sizes, int n_in,
                              void* d_out, int out_size, void* d_ws, size_t ws_size,
                              hipStream_t stream) {
  const float* query = (const float*)d_in[0];
  const float* keys  = (const float*)d_in[1];
  const float* values= (const float*)d_in[2];
  const float* awc   = (const float*)d_in[3];
  const unsigned char* mask = (const unsigned char*)d_in[4];
  const float* Wc    = (const float*)d_in[5];
  const float* Wlp   = (const float*)d_in[6];
  const float* Wq    = (const float*)d_in[7];
  const float* Wk    = (const float*)d_in[8];
  const float* Wv    = (const float*)d_in[9];
  const float* Wa    = (const float*)d_in[10];

  float* ctx  = (float*)d_out;              // (64,512)
  float* attn = (float*)d_out + B_ * ED;    // (64,1024)

  float* ws = (float*)d_ws;
  float* qp      = ws;                                     // 8192 f
  float* scoresB = qp + B_ * AD;                           // 65536 f
  float* wvp     = scoresB + B_ * T_;                      // 1048576 f
  short* Wk16    = (short*)(wvp + (size_t)B_ * 32 * ED);   // 65536 sh
  short* Wlp16   = Wk16 + AD * ED;                         // 4096 sh
  short* loc_g   = Wlp16 + AD * NF;                        // 2097152 sh
  short* keys16  = loc_g + (size_t)B_ * T_ * NF;           // 33554432 sh

  prep_kernel<<<KB_ + 68 + 512 + 64, 256, 0, stream>>>(
      keys, Wk, Wlp, awc, Wc, query, Wq, keys16, Wk16, Wlp16, loc_g, qp);
  scores_kernel<<<dim3(8, B_), 256, 0, stream>>>(keys16, Wk16, Wlp16, loc_g,
                                                 qp, Wa, scoresB);
  softmax_kernel<<<B_, 256, 0, stream>>>(scoresB, mask, attn);
  wvsum_kernel<<<dim3(16, B_), 256, 0, stream>>>(values, attn, wvp);
  context_kernel<<<dim3(4, B_), 256, 0, stream>>>(wvp, Wv, ctx);
}